// Round 12
// baseline (271.650 us; speedup 1.0000x reference)
//
#include <hip/hip_runtime.h>
#include <stdint.h>

#define E_N 600000
#define N_N 100000

typedef short short8   __attribute__((ext_vector_type(8)));
typedef short short8a  __attribute__((ext_vector_type(8), may_alias));
typedef float floatx4  __attribute__((ext_vector_type(4)));
typedef float floatx2  __attribute__((ext_vector_type(2)));
typedef float floatx4a __attribute__((ext_vector_type(4), may_alias));
typedef float floatx8a __attribute__((ext_vector_type(8), may_alias));
typedef unsigned int uintx2  __attribute__((ext_vector_type(2)));
typedef unsigned int uintx2a __attribute__((ext_vector_type(2), may_alias));
typedef unsigned int uintx4  __attribute__((ext_vector_type(4)));
typedef unsigned int uintx4a __attribute__((ext_vector_type(4), may_alias));
typedef __bf16 bf16x4 __attribute__((ext_vector_type(4)));
typedef __bf16 bf16x8 __attribute__((ext_vector_type(8)));

static __device__ __forceinline__ unsigned short f2bf(float f){
  unsigned u = __builtin_bit_cast(unsigned, f);
  unsigned rnd = 0x7fffu + ((u >> 16) & 1u);
  return (unsigned short)((u + rnd) >> 16);
}
static __device__ __forceinline__ unsigned pk2(float a, float b){
  floatx2 f; f[0] = a; f[1] = b;
  typedef __bf16 bf16x2 __attribute__((ext_vector_type(2)));
  return __builtin_bit_cast(unsigned, __builtin_convertvector(f, bf16x2));
}

// ---- prep: weights -> bf16, swizzled; W1 three 32KB k-windows (k=128), W2 one.
// u16 index: win*16384 + (c*64 + ((kp>>1) ^ ((c&7)<<2)))*2 + (kp&1)
__global__ void prep_weights(const float* __restrict__ W1, const float* __restrict__ W2,
                             unsigned short* __restrict__ w1s, unsigned short* __restrict__ w2s){
  int i = blockIdx.x * 256 + threadIdx.x;
  if (i < 384 * 128){
    int c = i / 384, k = i - c * 384;
    int p = k >> 7, kp = k & 127;
    int dw = c * 64 + ((kp >> 1) ^ ((c & 7) << 2));
    w1s[p * 16384 + dw * 2 + (kp & 1)] = f2bf(W1[k * 128 + c]);
  } else {
    int j = i - 384 * 128;            // grid sized exactly: j < 16384
    int c = j >> 7, k = j & 127;
    int dw = c * 64 + ((k >> 1) ^ ((c & 7) << 2));
    w2s[dw * 2 + (k & 1)] = f2bf(W2[k * 128 + c]);
  }
}

// ---- prep: copy nfeat -> output[1]; nfeat f32 -> bf16 in ws
__global__ void prep_nfeat(const float* __restrict__ nf,
                           unsigned* __restrict__ nfbu,
                           float* __restrict__ out2){
  const int total = N_N * 128 / 4;
  int stride = gridDim.x * blockDim.x;
  for (int i = blockIdx.x * blockDim.x + threadIdx.x; i < total; i += stride){
    float4 v = reinterpret_cast<const float4*>(nf)[i];
    reinterpret_cast<float4*>(out2)[i] = v;
    nfbu[2 * i]     = pk2(v.x, v.y);
    nfbu[2 * i + 1] = pk2(v.z, v.w);
  }
}

static __device__ __forceinline__ void glds16(void* lds, const void* g){
  __builtin_amdgcn_global_load_lds((const __attribute__((address_space(1))) unsigned int*)g,
                                   (__attribute__((address_space(3))) unsigned int*)lds,
                                   16, 0, 0);
}

// ---- fused, operand-swapped, BARRIER-FREE steady state:
// W1+W2 fully LDS-resident (128KB), 8 waves x 32 edges, one sync after staging.
// Each wave independently: GEMM1 -> silu -> GEMM2 (2 passes via 4KB tile + hpk)
// -> LN -> store. Waves drift out of phase; pipes overlap across waves.
__global__ __launch_bounds__(512, 2) void fused_edge(
    const float* __restrict__ efeat,
    const int* __restrict__ src_idx, const int* __restrict__ dst_idx,
    const unsigned short* __restrict__ nfb,
    const unsigned short* __restrict__ w1s,   // w2s contiguous at +98304 B
    const float* __restrict__ b1, const float* __restrict__ b2,
    const float* __restrict__ lns, const float* __restrict__ lnb,
    float* __restrict__ out)
{
  // [0, 98304)        : W1 swizzled bf16 (3 windows of 32KB)
  // [98304, 131072)   : W2 swizzled bf16
  // [131072, 163840)  : per-wave h/residual tile, 4 KB each ([16][64 dw], swizzled)
  __shared__ __align__(16) unsigned char smem[163840];
  unsigned int* wlds = (unsigned int*)smem;

  const int tid  = threadIdx.x;
  const int w    = tid >> 6;
  const int lane = tid & 63;
  const int r    = lane & 15;     // A row (chan) / B col (edge)
  const int g    = lane >> 4;     // k-group; D row = 4g+q
  const int sw8  = (r & 7) << 2;  // dword XOR swizzle

  unsigned int* tile = (unsigned int*)(smem + 131072 + w * 4096);

  // stage W1+W2 (131072 B contiguous in ws): 16 rounds x 512 thr x 16 B
  #pragma unroll
  for (int rnd = 0; rnd < 16; ++rnd){
    int off = rnd * 8192 + tid * 16;
    glds16(smem + off, (const unsigned char*)w1s + off);
  }

  const int eb = blockIdx.x * 256 + w * 32;
  const int e0 = eb + r, e1 = eb + 16 + r;
  const int e0c = e0 < E_N ? e0 : (E_N - 1);
  const int e1c = e1 < E_N ? e1 : (E_N - 1);
  int s0 = src_idx[e0c], d0 = dst_idx[e0c];
  int s1 = src_idx[e1c], d1 = dst_idx[e1c];
  s0 = s0 < 0 ? 0 : (s0 >= N_N ? N_N - 1 : s0);
  d0 = d0 < 0 ? 0 : (d0 >= N_N ? N_N - 1 : d0);
  s1 = s1 < 0 ? 0 : (s1 >= N_N ? N_N - 1 : s1);
  d1 = d1 < 0 ? 0 : (d1 >= N_N ? N_N - 1 : d1);

  auto loadX_f32 = [&](const float* p) -> short8 {
    floatx8a f = *reinterpret_cast<const floatx8a*>(p);
    return __builtin_bit_cast(short8, __builtin_convertvector(f, bf16x8));
  };

  // prefetch both 16-edge halves' X working sets (24 short8 = 96 VGPR),
  // overlapping the W staging latency; the barrier drains both.
  short8 xa[12], xb[12];
  #pragma unroll
  for (int kf = 0; kf < 4; ++kf){
    xa[kf] = loadX_f32(efeat + (size_t)e0c * 128 + kf * 32 + 8 * g);
    xb[kf] = loadX_f32(efeat + (size_t)e1c * 128 + kf * 32 + 8 * g);
  }
  #pragma unroll
  for (int kf = 0; kf < 4; ++kf){
    xa[4 + kf] = *reinterpret_cast<const short8a*>(nfb + (size_t)s0 * 128 + kf * 32 + 8 * g);
    xb[4 + kf] = *reinterpret_cast<const short8a*>(nfb + (size_t)s1 * 128 + kf * 32 + 8 * g);
  }
  #pragma unroll
  for (int kf = 0; kf < 4; ++kf){
    xa[8 + kf] = *reinterpret_cast<const short8a*>(nfb + (size_t)d0 * 128 + kf * 32 + 8 * g);
    xb[8 + kf] = *reinterpret_cast<const short8a*>(nfb + (size_t)d1 * 128 + kf * 32 + 8 * g);
  }

  __syncthreads();   // W resident + X prefetched; LAST barrier in the kernel

  // W1 frag: window p, row 16m+r, local k = k4*32+8g (row = 64 dwords)
  auto loadW1L = [&](int p, int m, int k4) -> short8 {
    uintx4a v = *reinterpret_cast<const uintx4a*>(
        &wlds[p * 8192 + (16 * m + r) * 64 + ((k4 * 16 + 4 * g) ^ sw8)]);
    return __builtin_bit_cast(short8, v);
  };
  auto loadW2L = [&](int m, int ks) -> short8 {
    uintx4a v = *reinterpret_cast<const uintx4a*>(
        &wlds[24576 + (16 * m + r) * 64 + ((ks * 16 + 4 * g) ^ sw8)]);
    return __builtin_bit_cast(short8, v);
  };

  // ---- GEMM1: both halves, W frag loaded once, used twice
  floatx4 acc1[2][8];
  #pragma unroll
  for (int e2 = 0; e2 < 2; ++e2)
    #pragma unroll
    for (int mi = 0; mi < 8; ++mi)
      acc1[e2][mi] = (floatx4){0.f, 0.f, 0.f, 0.f};

  #pragma unroll
  for (int p = 0; p < 3; ++p){
    #pragma unroll
    for (int k4 = 0; k4 < 4; ++k4){
      short8 x0 = xa[p * 4 + k4];
      short8 x1 = xb[p * 4 + k4];
      #pragma unroll
      for (int mi = 0; mi < 8; ++mi){
        short8 wf = loadW1L(p, mi, k4);
        acc1[0][mi] = __builtin_amdgcn_mfma_f32_16x16x32_bf16(wf, x0, acc1[0][mi], 0, 0, 0);
        acc1[1][mi] = __builtin_amdgcn_mfma_f32_16x16x32_bf16(wf, x1, acc1[1][mi], 0, 0, 0);
      }
    }
  }

  // ---- epilogue 1: +b1 (L2-hot broadcast loads), silu, pack.
  // half 0 -> tile, half 1 -> 16 VGPRs (hpk)
  uintx2 hpk[8];
  #pragma unroll
  for (int mi = 0; mi < 8; ++mi){
    floatx4 bb = *reinterpret_cast<const floatx4a*>(b1 + 16 * mi + 4 * g);
    floatx4 v0, v1;
    #pragma unroll
    for (int q = 0; q < 4; ++q){
      float x0 = acc1[0][mi][q] + bb[q];
      float x1 = acc1[1][mi][q] + bb[q];
      v0[q] = x0 * __builtin_amdgcn_rcpf(1.f + __expf(-x0));
      v1[q] = x1 * __builtin_amdgcn_rcpf(1.f + __expf(-x1));
    }
    *reinterpret_cast<uintx2a*>(&tile[r * 64 + ((8 * mi + 2 * g) ^ sw8)]) =
        __builtin_bit_cast(uintx2, __builtin_convertvector(v0, bf16x4));
    hpk[mi] = __builtin_bit_cast(uintx2, __builtin_convertvector(v1, bf16x4));
  }

  // ---- per half: GEMM2 + LN + store (wave-private tile, in-order DS pipe)
  #pragma unroll
  for (int e2 = 0; e2 < 2; ++e2){
    if (e2 == 1){
      #pragma unroll
      for (int mi = 0; mi < 8; ++mi)
        *reinterpret_cast<uintx2a*>(&tile[r * 64 + ((8 * mi + 2 * g) ^ sw8)]) = hpk[mi];
    }

    floatx4 acc2[8];
    #pragma unroll
    for (int mo = 0; mo < 8; ++mo)
      acc2[mo] = (floatx4){0.f, 0.f, 0.f, 0.f};

    #pragma unroll
    for (int ks = 0; ks < 4; ++ks){
      uintx4a hv = *reinterpret_cast<const uintx4a*>(&tile[r * 64 + ((ks * 16 + 4 * g) ^ sw8)]);
      short8 hb = __builtin_bit_cast(short8, hv);
      #pragma unroll
      for (int mo = 0; mo < 8; ++mo){
        short8 wf = loadW2L(mo, ks);
        acc2[mo] = __builtin_amdgcn_mfma_f32_16x16x32_bf16(wf, hb, acc2[mo], 0, 0, 0);
      }
    }

    // residual handoff: overwrite tile with this half's bf16 efeat frags
    #pragma unroll
    for (int kf = 0; kf < 4; ++kf)
      *reinterpret_cast<uintx4a*>(&tile[r * 64 + ((16 * kf + 4 * g) ^ sw8)]) =
          __builtin_bit_cast(uintx4, e2 == 0 ? xa[kf] : xb[kf]);

    float s1 = 0.f, s2 = 0.f;
    #pragma unroll
    for (int mo = 0; mo < 8; ++mo){
      floatx4 bb = *reinterpret_cast<const floatx4a*>(b2 + 16 * mo + 4 * g);
      #pragma unroll
      for (int q = 0; q < 4; ++q){
        float v = acc2[mo][q] + bb[q];
        s1 += v; s2 += v * v;
      }
    }
    s1 += __shfl_xor(s1, 16); s2 += __shfl_xor(s2, 16);
    s1 += __shfl_xor(s1, 32); s2 += __shfl_xor(s2, 32);

    float mu   = s1 * (1.f / 128.f);
    float var  = s2 * (1.f / 128.f) - mu * mu;
    var = var > 0.f ? var : 0.f;
    float rstd = __builtin_amdgcn_rsqf(var + 1e-5f);

    const int e = e2 == 0 ? e0 : e1;
    if (e < E_N){
      float* op = out + (size_t)e * 128;
      #pragma unroll
      for (int mo = 0; mo < 8; ++mo){
        int c = 16 * mo + 4 * g;
        floatx4 bb = *reinterpret_cast<const floatx4a*>(b2  + c);
        floatx4 ls = *reinterpret_cast<const floatx4a*>(lns + c);
        floatx4 lb = *reinterpret_cast<const floatx4a*>(lnb + c);
        uintx2a rv = *reinterpret_cast<const uintx2a*>(&tile[r * 64 + ((8 * mo + 2 * g) ^ sw8)]);
        floatx4 e4;
        e4[0] = __builtin_bit_cast(float, rv[0] << 16);
        e4[1] = __builtin_bit_cast(float, rv[0] & 0xffff0000u);
        e4[2] = __builtin_bit_cast(float, rv[1] << 16);
        e4[3] = __builtin_bit_cast(float, rv[1] & 0xffff0000u);
        floatx4 o4;
        #pragma unroll
        for (int q = 0; q < 4; ++q)
          o4[q] = (acc2[mo][q] + bb[q] - mu) * rstd * ls[q] + lb[q] + e4[q];
        *reinterpret_cast<floatx4a*>(op + c) = o4;
      }
    }
  }
}

extern "C" void kernel_launch(void* const* d_in, const int* in_sizes, int n_in,
                              void* d_out, int out_size, void* d_ws, size_t ws_size,
                              hipStream_t stream){
  const float* efeat = (const float*)d_in[0];
  const float* nfeat = (const float*)d_in[1];
  const int*   srci  = (const int*)d_in[2];
  const int*   dsti  = (const int*)d_in[3];
  const float* W1    = (const float*)d_in[4];
  const float* b1    = (const float*)d_in[5];
  const float* W2    = (const float*)d_in[6];
  const float* b2    = (const float*)d_in[7];
  const float* lns   = (const float*)d_in[8];
  const float* lnb   = (const float*)d_in[9];
  float* out = (float*)d_out;

  char* ws = (char*)d_ws;
  unsigned short* w1s = (unsigned short*)ws;               // 98,304 B (3 swizzled windows)
  unsigned short* w2s = (unsigned short*)(ws + 98304);     // 32,768 B (swizzled, contiguous)
  unsigned short* nfb = (unsigned short*)(ws + 131072);    // 25,600,000 B

  prep_weights<<<(384 * 128 + 128 * 128) / 256, 256, 0, stream>>>(W1, W2, w1s, w2s);
  prep_nfeat<<<2048, 256, 0, stream>>>(nfeat, (unsigned*)nfb, out + (size_t)E_N * 128);

  int blocks = (E_N + 255) / 256;   // 2344
  fused_edge<<<blocks, 512, 0, stream>>>(efeat, srci, dsti, nfb, w1s,
                                         b1, b2, lns, lnb, out);
}

// Round 13
// 231.067 us; speedup vs baseline: 1.1756x; 1.1756x over previous
//
#include <hip/hip_runtime.h>
#include <stdint.h>

#define E_N 600000
#define N_N 100000

typedef short short8   __attribute__((ext_vector_type(8)));
typedef short short8a  __attribute__((ext_vector_type(8), may_alias));
typedef float floatx2  __attribute__((ext_vector_type(2)));
typedef float floatx4  __attribute__((ext_vector_type(4)));
typedef float floatx16 __attribute__((ext_vector_type(16)));
typedef float floatx4a __attribute__((ext_vector_type(4), may_alias));
typedef float floatx8a __attribute__((ext_vector_type(8), may_alias));
typedef unsigned int uintx2  __attribute__((ext_vector_type(2)));
typedef unsigned int uintx4  __attribute__((ext_vector_type(4)));
typedef unsigned int uintx4a __attribute__((ext_vector_type(4), may_alias));
typedef __bf16 bf16x4 __attribute__((ext_vector_type(4)));
typedef __bf16 bf16x8 __attribute__((ext_vector_type(8)));

static __device__ __forceinline__ unsigned short f2bf(float f){
  unsigned u = __builtin_bit_cast(unsigned, f);
  unsigned rnd = 0x7fffu + ((u >> 16) & 1u);
  return (unsigned short)((u + rnd) >> 16);
}
static __device__ __forceinline__ unsigned pk2(float a, float b){
  floatx2 f; f[0] = a; f[1] = b;
  typedef __bf16 bf16x2 __attribute__((ext_vector_type(2)));
  return __builtin_bit_cast(unsigned, __builtin_convertvector(f, bf16x2));
}

// ---- prep: weights -> bf16, EIGHT 16KB windows (k=64 each; rows=128 chans, 32 dw):
// wins 0..5 = W1 (k 0..383), wins 6..7 = W2 (k 0..127).
// u16 index: win*8192 + (c*32 + ((kp>>1) ^ ((c&7)<<2)))*2 + (kp&1)
__global__ void prep_weights(const float* __restrict__ W1, const float* __restrict__ W2,
                             unsigned short* __restrict__ wall){
  int i = blockIdx.x * 256 + threadIdx.x;
  int c, k, win; float v;
  if (i < 384 * 128){
    c = i / 384; k = i - c * 384; win = k >> 6;
    v = W1[k * 128 + c];
  } else {
    int j = i - 384 * 128;            // grid exact: j < 16384
    c = j >> 7; k = j & 127; win = 6 + (k >> 6);
    v = W2[k * 128 + c];
  }
  int kp = k & 63;
  wall[win * 8192 + (c * 32 + ((kp >> 1) ^ ((c & 7) << 2))) * 2 + (kp & 1)] = f2bf(v);
}

// ---- prep: copy nfeat -> output[1]; nfeat f32 -> bf16 in ws
__global__ void prep_nfeat(const float* __restrict__ nf,
                           unsigned* __restrict__ nfbu,
                           float* __restrict__ out2){
  const int total = N_N * 128 / 4;
  int stride = gridDim.x * blockDim.x;
  for (int i = blockIdx.x * blockDim.x + threadIdx.x; i < total; i += stride){
    float4 v = reinterpret_cast<const float4*>(nf)[i];
    reinterpret_cast<float4*>(out2)[i] = v;
    nfbu[2 * i]     = pk2(v.x, v.y);
    nfbu[2 * i + 1] = pk2(v.z, v.w);
  }
}

static __device__ __forceinline__ void glds16(void* lds, const void* g){
  __builtin_amdgcn_global_load_lds((const __attribute__((address_space(1))) unsigned int*)g,
                                   (__attribute__((address_space(3))) unsigned int*)lds,
                                   16, 0, 0);
}

// ---- fused, 32x32x16 MFMA, operand-swapped: h^T = W1^T X^T ; y^T = W2^T h^T
// 256 thr = 4 waves x 32 edges. Double-buffered 16KB W windows (r11 scaffold).
// GEMM1->GEMM2 handoff and the efeat residual are done ENTIRELY in registers
// via lane<->lane+32 shfl_xor swaps (no h tile, no residual tile, no efeat
// re-read). LDS = 34KB -> 3 blocks/CU at <=170 VGPR (launch_bounds 256,3).
__global__ __launch_bounds__(256, 3) void fused_edge(
    const float* __restrict__ efeat,
    const int* __restrict__ src_idx, const int* __restrict__ dst_idx,
    const unsigned short* __restrict__ nfb,
    const unsigned short* __restrict__ wall,
    const float* __restrict__ b1, const float* __restrict__ b2,
    const float* __restrict__ lns, const float* __restrict__ lnb,
    float* __restrict__ out)
{
  // [0, 32768)      : two 16KB W buffers
  // [32768, 34816)  : biases: b1 | b2 | ln_scale | ln_bias (128 f32 each)
  __shared__ __align__(16) unsigned char smem[34816];
  unsigned int* wbuf  = (unsigned int*)smem;
  float*        cmisc = (float*)(smem + 32768);

  const int tid  = threadIdx.x;
  const int w    = tid >> 6;
  const int lane = tid & 63;
  const int rl   = lane & 31;     // A row (chan) / B col (edge) / D col (edge)
  const int hi   = lane >> 5;     // k-half; D row-offset 4*hi
  const int swz  = (rl & 7) << 2; // dword XOR swizzle (b128-aligned)

  auto stageW = [&](int b, int win){
    const unsigned char* src = (const unsigned char*)wall + win * 16384;
    #pragma unroll
    for (int rnd = 0; rnd < 4; ++rnd){
      int off = rnd * 4096 + tid * 16;
      glds16(smem + b * 16384 + off, src + off);
    }
  };

  stageW(0, 0);
  cmisc[tid]       = tid < 128 ? b1[tid]  : b2[tid - 128];
  cmisc[tid + 256] = tid < 128 ? lns[tid] : lnb[tid - 128];

  const int e0 = blockIdx.x * 128 + w * 32 + rl;
  const int ec = e0 < E_N ? e0 : (E_N - 1);
  int si = src_idx[ec], di = dst_idx[ec];
  si = si < 0 ? 0 : (si >= N_N ? N_N - 1 : si);
  di = di < 0 ? 0 : (di >= N_N ? N_N - 1 : di);

  // X B-frag loads: elem (lane, j) = X[edge rl][k = ks8*16 + hi*8 + j]
  auto ldE = [&](int ks8) -> short8 {
    floatx8a f = *reinterpret_cast<const floatx8a*>(efeat + (size_t)ec * 128 + ks8 * 16 + hi * 8);
    return __builtin_bit_cast(short8, __builtin_convertvector(f, bf16x8));
  };
  auto ldG = [&](int row, int ks8) -> short8 {
    return *reinterpret_cast<const short8a*>(nfb + (size_t)row * 128 + ks8 * 16 + hi * 8);
  };

  // prefetch: efeat (kept for residual) + first gather window
  short8 xe[8], xc[4], xn[4];
  #pragma unroll
  for (int ks8 = 0; ks8 < 8; ++ks8) xe[ks8] = ldE(ks8);
  #pragma unroll
  for (int k = 0; k < 4; ++k) xc[k] = ldG(si, k);

  __syncthreads();   // window 0 + cmisc ready

  // W A-frag: buffer b, m-tile m, kstep ks: row = 32m+rl, dwords (ks*8+hi*4)^swz
  auto loadW = [&](int b, int m, int ks) -> short8 {
    uintx4a v = *reinterpret_cast<const uintx4a*>(
        &wbuf[b * 4096 + (32 * m + rl) * 32 + ((ks * 8 + hi * 4) ^ swz)]);
    return __builtin_bit_cast(short8, v);
  };

  floatx16 acc1[4];
  #pragma unroll
  for (int mt = 0; mt < 4; ++mt)
    #pragma unroll
    for (int q = 0; q < 16; ++q) acc1[mt][q] = 0.f;

  auto g1win = [&](int b, const short8* xs){
    #pragma unroll
    for (int ks = 0; ks < 4; ++ks){
      #pragma unroll
      for (int mt = 0; mt < 4; ++mt){
        short8 wf = loadW(b, mt, ks);
        acc1[mt] = __builtin_amdgcn_mfma_f32_32x32x16_bf16(wf, xs[ks], acc1[mt], 0, 0, 0);
      }
    }
  };

  // ---- GEMM1: 6 double-buffered W1 windows (k=64), X prefetched 2+ ahead
  stageW(1, 1);
  #pragma unroll
  for (int k = 0; k < 4; ++k) xn[k] = ldG(si, 4 + k);
  g1win(0, xe);
  __syncthreads();

  stageW(0, 2);
  g1win(1, xe + 4);
  __syncthreads();

  stageW(1, 3);
  g1win(0, xc);
  #pragma unroll
  for (int k = 0; k < 4; ++k) xc[k] = ldG(di, k);
  __syncthreads();

  stageW(0, 4);
  g1win(1, xn);
  #pragma unroll
  for (int k = 0; k < 4; ++k) xn[k] = ldG(di, 4 + k);
  __syncthreads();

  stageW(1, 5);
  g1win(0, xc);
  __syncthreads();

  stageW(0, 6);              // W2 first half
  g1win(1, xn);
  __syncthreads();

  // ---- h-frag build IN REGISTERS: silu(acc1+b1) -> bf16 packs -> lane<->lane+32
  // swap. B-frag(ks=2mt+k1): hi=0 lane: [own P(k1,0) | partner P(k1,0)],
  //                          hi=1 lane: [partner P(k1,1) | own P(k1,1)].
  short8 hfr[8];
  #pragma unroll
  for (int mt = 0; mt < 4; ++mt){
    floatx4 sv[4];
    #pragma unroll
    for (int p = 0; p < 4; ++p){
      floatx4 bb = *reinterpret_cast<const floatx4a*>(&cmisc[32 * mt + 8 * p + 4 * hi]);
      #pragma unroll
      for (int i = 0; i < 4; ++i){
        float xx = acc1[mt][4 * p + i] + bb[i];
        sv[p][i] = xx * __builtin_amdgcn_rcpf(1.f + __expf(-xx));   // silu
      }
    }
    #pragma unroll
    for (int k1 = 0; k1 < 2; ++k1){
      uintx2 P0 = __builtin_bit_cast(uintx2, __builtin_convertvector(sv[2 * k1],     bf16x4));
      uintx2 P1 = __builtin_bit_cast(uintx2, __builtin_convertvector(sv[2 * k1 + 1], bf16x4));
      unsigned sA = hi ? P0[0] : P1[0];
      unsigned sB = hi ? P0[1] : P1[1];
      unsigned rA = __shfl_xor(sA, 32);
      unsigned rB = __shfl_xor(sB, 32);
      uintx4 u;
      u[0] = hi ? rA : P0[0];
      u[1] = hi ? rB : P0[1];
      u[2] = hi ? P1[0] : rA;
      u[3] = hi ? P1[1] : rB;
      hfr[2 * mt + k1] = __builtin_bit_cast(short8, u);
    }
  }

  // ---- residual exchange: xe frags -> (kept, received) half-packs
  uintx2 rk[8], rr[8];
  #pragma unroll
  for (int ks = 0; ks < 8; ++ks){
    uintx4 u = __builtin_bit_cast(uintx4, xe[ks]);
    unsigned sA = hi ? u[0] : u[2];
    unsigned sB = hi ? u[1] : u[3];
    rr[ks][0] = __shfl_xor(sA, 32);
    rr[ks][1] = __shfl_xor(sB, 32);
    rk[ks][0] = hi ? u[2] : u[0];
    rk[ks][1] = hi ? u[3] : u[1];
  }

  // ---- GEMM2: 2 W2 windows (win6 in buf0 ready; stage win7 -> buf1)
  floatx16 acc2[4];
  #pragma unroll
  for (int mo = 0; mo < 4; ++mo)
    #pragma unroll
    for (int q = 0; q < 16; ++q) acc2[mo][q] = 0.f;

  stageW(1, 7);
  #pragma unroll
  for (int ks = 0; ks < 4; ++ks)
    #pragma unroll
    for (int mo = 0; mo < 4; ++mo)
      acc2[mo] = __builtin_amdgcn_mfma_f32_32x32x16_bf16(loadW(0, mo, ks), hfr[ks], acc2[mo], 0, 0, 0);
  __syncthreads();
  #pragma unroll
  for (int ks = 0; ks < 4; ++ks)
    #pragma unroll
    for (int mo = 0; mo < 4; ++mo)
      acc2[mo] = __builtin_amdgcn_mfma_f32_32x32x16_bf16(loadW(1, mo, ks), hfr[4 + ks], acc2[mo], 0, 0, 0);

  // ---- LN (1 shuffle pair), residual from rk/rr, float4 stores
  float s1 = 0.f, s2 = 0.f;
  #pragma unroll
  for (int mt = 0; mt < 4; ++mt)
    #pragma unroll
    for (int p = 0; p < 4; ++p){
      floatx4 bb = *reinterpret_cast<const floatx4a*>(&cmisc[128 + 32 * mt + 8 * p + 4 * hi]);
      #pragma unroll
      for (int i = 0; i < 4; ++i){
        float v = acc2[mt][4 * p + i] + bb[i];
        s1 += v; s2 += v * v;
      }
    }
  s1 += __shfl_xor(s1, 32); s2 += __shfl_xor(s2, 32);

  float mu   = s1 * (1.f / 128.f);
  float var  = s2 * (1.f / 128.f) - mu * mu;
  var = var > 0.f ? var : 0.f;
  float rstd = __builtin_amdgcn_rsqf(var + 1e-5f);

  if (e0 < E_N){
    float* op = out + (size_t)e0 * 128;
    #pragma unroll
    for (int mt = 0; mt < 4; ++mt)
      #pragma unroll
      for (int p = 0; p < 4; ++p){
        int c = 32 * mt + 8 * p + 4 * hi;
        floatx4 bb = *reinterpret_cast<const floatx4a*>(&cmisc[128 + c]);
        floatx4 ls = *reinterpret_cast<const floatx4a*>(&cmisc[256 + c]);
        floatx4 lb = *reinterpret_cast<const floatx4a*>(&cmisc[384 + c]);
        const int ks = 2 * mt + (p >> 1);
        uintx2 pk_ = ((p & 1) == hi) ? rk[ks] : rr[ks];
        floatx4 o4;
        #pragma unroll
        for (int i = 0; i < 4; ++i){
          unsigned dwv = pk_[i >> 1];
          float ef = __builtin_bit_cast(float, (i & 1) ? (dwv & 0xffff0000u) : (dwv << 16));
          o4[i] = (acc2[mt][4 * p + i] + bb[i] - mu) * rstd * ls[i] + lb[i] + ef;
        }
        *reinterpret_cast<floatx4a*>(op + c) = o4;
      }
  }
}

extern "C" void kernel_launch(void* const* d_in, const int* in_sizes, int n_in,
                              void* d_out, int out_size, void* d_ws, size_t ws_size,
                              hipStream_t stream){
  const float* efeat = (const float*)d_in[0];
  const float* nfeat = (const float*)d_in[1];
  const int*   srci  = (const int*)d_in[2];
  const int*   dsti  = (const int*)d_in[3];
  const float* W1    = (const float*)d_in[4];
  const float* b1    = (const float*)d_in[5];
  const float* W2    = (const float*)d_in[6];
  const float* b2    = (const float*)d_in[7];
  const float* lns   = (const float*)d_in[8];
  const float* lnb   = (const float*)d_in[9];
  float* out = (float*)d_out;

  char* ws = (char*)d_ws;
  unsigned short* wall = (unsigned short*)ws;              // 131,072 B (8 swizzled windows)
  unsigned short* nfb  = (unsigned short*)(ws + 131072);   // 25,600,000 B

  prep_weights<<<(384 * 128 + 128 * 128) / 256, 256, 0, stream>>>(W1, W2, wall);
  prep_nfeat<<<2048, 256, 0, stream>>>(nfeat, (unsigned*)nfb, out + (size_t)E_N * 128);

  int blocks = (E_N + 127) / 128;   // 4688
  fused_edge<<<blocks, 256, 0, stream>>>(efeat, srci, dsti, nfb, wall,
                                         b1, b2, lns, lnb, out);
}

// Round 14
// 218.552 us; speedup vs baseline: 1.2430x; 1.0573x over previous
//
#include <hip/hip_runtime.h>
#include <stdint.h>

#define E_N 600000
#define N_N 100000

typedef short short8   __attribute__((ext_vector_type(8)));
typedef short short8a  __attribute__((ext_vector_type(8), may_alias));
typedef float floatx2  __attribute__((ext_vector_type(2)));
typedef float floatx4  __attribute__((ext_vector_type(4)));
typedef float floatx16 __attribute__((ext_vector_type(16)));
typedef float floatx4a __attribute__((ext_vector_type(4), may_alias));
typedef float floatx8a __attribute__((ext_vector_type(8), may_alias));
typedef unsigned int uintx2  __attribute__((ext_vector_type(2)));
typedef unsigned int uintx4  __attribute__((ext_vector_type(4)));
typedef unsigned int uintx4a __attribute__((ext_vector_type(4), may_alias));
typedef __bf16 bf16x4 __attribute__((ext_vector_type(4)));
typedef __bf16 bf16x8 __attribute__((ext_vector_type(8)));

static __device__ __forceinline__ unsigned short f2bf(float f){
  unsigned u = __builtin_bit_cast(unsigned, f);
  unsigned rnd = 0x7fffu + ((u >> 16) & 1u);
  return (unsigned short)((u + rnd) >> 16);
}
static __device__ __forceinline__ unsigned pk2(float a, float b){
  floatx2 f; f[0] = a; f[1] = b;
  typedef __bf16 bf16x2 __attribute__((ext_vector_type(2)));
  return __builtin_bit_cast(unsigned, __builtin_convertvector(f, bf16x2));
}

// counted-vmcnt phase boundary: wait for all loads except the last N, then
// raw barrier; memory-clobber asm on both sides pins LDS reads/loads in place.
#define WAITBAR(N) do{ \
  asm volatile("s_waitcnt vmcnt(" #N ")" ::: "memory"); \
  __builtin_amdgcn_s_barrier(); \
  asm volatile("" ::: "memory"); }while(0)
#define BARONLY() do{ \
  asm volatile("" ::: "memory"); \
  __builtin_amdgcn_s_barrier(); \
  asm volatile("" ::: "memory"); }while(0)

// ---- prep: weights -> bf16, EIGHT 16KB windows (k=64 each; rows=128 chans, 32 dw):
// wins 0..5 = W1 (k 0..383), wins 6..7 = W2 (k 0..127).
// u16 index: win*8192 + (c*32 + ((kp>>1) ^ ((c&7)<<2)))*2 + (kp&1)
__global__ void prep_weights(const float* __restrict__ W1, const float* __restrict__ W2,
                             unsigned short* __restrict__ wall){
  int i = blockIdx.x * 256 + threadIdx.x;
  int c, k, win; float v;
  if (i < 384 * 128){
    c = i / 384; k = i - c * 384; win = k >> 6;
    v = W1[k * 128 + c];
  } else {
    int j = i - 384 * 128;            // grid exact: j < 16384
    c = j >> 7; k = j & 127; win = 6 + (k >> 6);
    v = W2[k * 128 + c];
  }
  int kp = k & 63;
  wall[win * 8192 + (c * 32 + ((kp >> 1) ^ ((c & 7) << 2))) * 2 + (kp & 1)] = f2bf(v);
}

// ---- prep: copy nfeat -> output[1]; nfeat f32 -> bf16 in ws
__global__ void prep_nfeat(const float* __restrict__ nf,
                           unsigned* __restrict__ nfbu,
                           float* __restrict__ out2){
  const int total = N_N * 128 / 4;
  int stride = gridDim.x * blockDim.x;
  for (int i = blockIdx.x * blockDim.x + threadIdx.x; i < total; i += stride){
    float4 v = reinterpret_cast<const float4*>(nf)[i];
    reinterpret_cast<float4*>(out2)[i] = v;
    nfbu[2 * i]     = pk2(v.x, v.y);
    nfbu[2 * i + 1] = pk2(v.z, v.w);
  }
}

static __device__ __forceinline__ void glds16(void* lds, const void* g){
  __builtin_amdgcn_global_load_lds((const __attribute__((address_space(1))) unsigned int*)g,
                                   (__attribute__((address_space(3))) unsigned int*)lds,
                                   16, 0, 0);
}

// ---- fused, 32x32x16 MFMA, operand-swapped, COUNTED-VMCNT pipeline:
// 256 thr = 4 waves x 32 edges. THREE 16KB W buffers; stages and gathers are
// issued 2 windows ahead and stay in flight across barriers (vmcnt(8)/(4),
// never 0 mid-loop). In-register GEMM1->GEMM2 handoff + residual (r13).
__global__ __launch_bounds__(256, 3) void fused_edge(
    const float* __restrict__ efeat,
    const int* __restrict__ src_idx, const int* __restrict__ dst_idx,
    const unsigned short* __restrict__ nfb,
    const unsigned short* __restrict__ wall,
    const float* __restrict__ b1, const float* __restrict__ b2,
    const float* __restrict__ lns, const float* __restrict__ lnb,
    float* __restrict__ out)
{
  // [0, 49152)      : three 16KB W buffers
  // [49152, 51200)  : biases: b1 | b2 | ln_scale | ln_bias (128 f32 each)
  __shared__ __align__(16) unsigned char smem[51200];
  unsigned int* wbuf  = (unsigned int*)smem;
  float*        cmisc = (float*)(smem + 49152);

  const int tid  = threadIdx.x;
  const int w    = tid >> 6;
  const int lane = tid & 63;
  const int rl   = lane & 31;     // A row (chan) / B col (edge) / D col (edge)
  const int hi   = lane >> 5;     // k-half; D row-offset 4*hi
  const int swz  = (rl & 7) << 2; // dword XOR swizzle (b128-aligned)

  auto stageW = [&](int b, int win){
    const unsigned char* src = (const unsigned char*)wall + win * 16384;
    #pragma unroll
    for (int rnd = 0; rnd < 4; ++rnd){
      int off = rnd * 4096 + tid * 16;
      glds16(smem + b * 16384 + off, src + off);
    }
  };

  // prologue: first two windows + biases + per-edge indices + efeat prefetch
  stageW(0, 0);
  stageW(1, 1);
  cmisc[tid]       = tid < 128 ? b1[tid]  : b2[tid - 128];
  cmisc[tid + 256] = tid < 128 ? lns[tid] : lnb[tid - 128];

  const int e0 = blockIdx.x * 128 + w * 32 + rl;
  const int ec = e0 < E_N ? e0 : (E_N - 1);
  int si = src_idx[ec], di = dst_idx[ec];
  si = si < 0 ? 0 : (si >= N_N ? N_N - 1 : si);
  di = di < 0 ? 0 : (di >= N_N ? N_N - 1 : di);

  auto ldE = [&](int ks8) -> short8 {
    floatx8a f = *reinterpret_cast<const floatx8a*>(efeat + (size_t)ec * 128 + ks8 * 16 + hi * 8);
    return __builtin_bit_cast(short8, __builtin_convertvector(f, bf16x8));
  };

  short8 xe[8], ga[4], gb[4];
  #pragma unroll
  for (int ks8 = 0; ks8 < 8; ++ks8) xe[ks8] = ldE(ks8);

  auto gather4 = [&](short8* dst, int row, int k0){
    #pragma unroll
    for (int k = 0; k < 4; ++k)
      dst[k] = *reinterpret_cast<const short8a*>(nfb + (size_t)row * 128 + (k0 + k) * 16 + hi * 8);
  };

  // W A-frag: buffer b, m-tile m, kstep ks: row = 32m+rl, dwords (ks*8+hi*4)^swz
  auto loadW = [&](int b, int m, int ks) -> short8 {
    uintx4a v = *reinterpret_cast<const uintx4a*>(
        &wbuf[b * 4096 + (32 * m + rl) * 32 + ((ks * 8 + hi * 4) ^ swz)]);
    return __builtin_bit_cast(short8, v);
  };

  floatx16 acc1[4];
  #pragma unroll
  for (int mt = 0; mt < 4; ++mt)
    #pragma unroll
    for (int q = 0; q < 16; ++q) acc1[mt][q] = 0.f;

  auto g1win = [&](int b, const short8* xs){
    __builtin_amdgcn_s_setprio(1);
    #pragma unroll
    for (int ks = 0; ks < 4; ++ks){
      #pragma unroll
      for (int mt = 0; mt < 4; ++mt){
        short8 wf = loadW(b, mt, ks);
        acc1[mt] = __builtin_amdgcn_mfma_f32_32x32x16_bf16(wf, xs[ks], acc1[mt], 0, 0, 0);
      }
    }
    __builtin_amdgcn_s_setprio(0);
  };

  // ---- 8-phase counted-vmcnt pipeline -------------------------------------
  WAITBAR(0);                         // prologue drain (once)

  // t=0: win0 (buf0, xe[0..3]); prefetch stage win2 + gather(si lo)
  stageW(2, 2);
  g1win(0, xe);
  gather4(ga, si, 0);

  // t=1: win1 (buf1, xe[4..7]); prefetch stage win3 + gather(si hi)
  BARONLY();
  stageW(0, 3);
  g1win(1, xe + 4);
  gather4(gb, si, 4);

  // t=2: win2 (buf2, ga); prefetch stage win4 + gather(di lo)
  WAITBAR(8);
  stageW(1, 4);
  g1win(2, ga);
  gather4(ga, di, 0);

  // t=3: win3 (buf0, gb); prefetch stage win5 + gather(di hi)
  WAITBAR(8);
  stageW(2, 5);
  g1win(0, gb);
  gather4(gb, di, 4);

  // t=4: win4 (buf1, ga); prefetch stage win6
  WAITBAR(8);
  stageW(0, 6);
  g1win(1, ga);

  // t=5: win5 (buf2, gb); prefetch stage win7; then retire acc1 in registers
  WAITBAR(4);
  stageW(1, 7);
  g1win(2, gb);

  // ---- h-frag build IN REGISTERS: silu(acc1+b1) -> bf16 -> lane<->lane+32
  short8 hfr[8];
  #pragma unroll
  for (int mt = 0; mt < 4; ++mt){
    floatx4 sv[4];
    #pragma unroll
    for (int p = 0; p < 4; ++p){
      floatx4 bb = *reinterpret_cast<const floatx4a*>(&cmisc[32 * mt + 8 * p + 4 * hi]);
      #pragma unroll
      for (int i = 0; i < 4; ++i){
        float xx = acc1[mt][4 * p + i] + bb[i];
        sv[p][i] = xx * __builtin_amdgcn_rcpf(1.f + __expf(-xx));   // silu
      }
    }
    #pragma unroll
    for (int k1 = 0; k1 < 2; ++k1){
      uintx2 P0 = __builtin_bit_cast(uintx2, __builtin_convertvector(sv[2 * k1],     bf16x4));
      uintx2 P1 = __builtin_bit_cast(uintx2, __builtin_convertvector(sv[2 * k1 + 1], bf16x4));
      unsigned sA = hi ? P0[0] : P1[0];
      unsigned sB = hi ? P0[1] : P1[1];
      unsigned rA = __shfl_xor(sA, 32);
      unsigned rB = __shfl_xor(sB, 32);
      uintx4 u;
      u[0] = hi ? rA : P0[0];
      u[1] = hi ? rB : P0[1];
      u[2] = hi ? P1[0] : rA;
      u[3] = hi ? P1[1] : rB;
      hfr[2 * mt + k1] = __builtin_bit_cast(short8, u);
    }
  }

  // ---- residual exchange: xe frags -> (kept, received) half-packs
  uintx2 rk[8], rr[8];
  #pragma unroll
  for (int ks = 0; ks < 8; ++ks){
    uintx4 u = __builtin_bit_cast(uintx4, xe[ks]);
    unsigned sA = hi ? u[0] : u[2];
    unsigned sB = hi ? u[1] : u[3];
    rr[ks][0] = __shfl_xor(sA, 32);
    rr[ks][1] = __shfl_xor(sB, 32);
    rk[ks][0] = hi ? u[2] : u[0];
    rk[ks][1] = hi ? u[3] : u[1];
  }

  floatx16 acc2[4];
  #pragma unroll
  for (int mo = 0; mo < 4; ++mo)
    #pragma unroll
    for (int q = 0; q < 16; ++q) acc2[mo][q] = 0.f;

  // t=6: GEMM2 first half (buf0 = win6, hfr[0..3])
  WAITBAR(4);
  __builtin_amdgcn_s_setprio(1);
  #pragma unroll
  for (int ks = 0; ks < 4; ++ks)
    #pragma unroll
    for (int mo = 0; mo < 4; ++mo)
      acc2[mo] = __builtin_amdgcn_mfma_f32_32x32x16_bf16(loadW(0, mo, ks), hfr[ks], acc2[mo], 0, 0, 0);
  __builtin_amdgcn_s_setprio(0);

  // t=7: GEMM2 second half (buf1 = win7, hfr[4..7])
  WAITBAR(0);
  __builtin_amdgcn_s_setprio(1);
  #pragma unroll
  for (int ks = 0; ks < 4; ++ks)
    #pragma unroll
    for (int mo = 0; mo < 4; ++mo)
      acc2[mo] = __builtin_amdgcn_mfma_f32_32x32x16_bf16(loadW(1, mo, ks), hfr[4 + ks], acc2[mo], 0, 0, 0);
  __builtin_amdgcn_s_setprio(0);

  // ---- LN (1 shuffle pair), residual from rk/rr, float4 stores
  float s1 = 0.f, s2 = 0.f;
  #pragma unroll
  for (int mt = 0; mt < 4; ++mt)
    #pragma unroll
    for (int p = 0; p < 4; ++p){
      floatx4 bb = *reinterpret_cast<const floatx4a*>(&cmisc[128 + 32 * mt + 8 * p + 4 * hi]);
      #pragma unroll
      for (int i = 0; i < 4; ++i){
        float v = acc2[mt][4 * p + i] + bb[i];
        s1 += v; s2 += v * v;
      }
    }
  s1 += __shfl_xor(s1, 32); s2 += __shfl_xor(s2, 32);

  float mu   = s1 * (1.f / 128.f);
  float var  = s2 * (1.f / 128.f) - mu * mu;
  var = var > 0.f ? var : 0.f;
  float rstd = __builtin_amdgcn_rsqf(var + 1e-5f);

  if (e0 < E_N){
    float* op = out + (size_t)e0 * 128;
    #pragma unroll
    for (int mt = 0; mt < 4; ++mt)
      #pragma unroll
      for (int p = 0; p < 4; ++p){
        int c = 32 * mt + 8 * p + 4 * hi;
        floatx4 bb = *reinterpret_cast<const floatx4a*>(&cmisc[128 + c]);
        floatx4 ls = *reinterpret_cast<const floatx4a*>(&cmisc[256 + c]);
        floatx4 lb = *reinterpret_cast<const floatx4a*>(&cmisc[384 + c]);
        const int ks = 2 * mt + (p >> 1);
        uintx2 pk_ = ((p & 1) == hi) ? rk[ks] : rr[ks];
        floatx4 o4;
        #pragma unroll
        for (int i = 0; i < 4; ++i){
          unsigned dwv = pk_[i >> 1];
          float ef = __builtin_bit_cast(float, (i & 1) ? (dwv & 0xffff0000u) : (dwv << 16));
          o4[i] = (acc2[mt][4 * p + i] + bb[i] - mu) * rstd * ls[i] + lb[i] + ef;
        }
        *reinterpret_cast<floatx4a*>(op + c) = o4;
      }
  }
}

extern "C" void kernel_launch(void* const* d_in, const int* in_sizes, int n_in,
                              void* d_out, int out_size, void* d_ws, size_t ws_size,
                              hipStream_t stream){
  const float* efeat = (const float*)d_in[0];
  const float* nfeat = (const float*)d_in[1];
  const int*   srci  = (const int*)d_in[2];
  const int*   dsti  = (const int*)d_in[3];
  const float* W1    = (const float*)d_in[4];
  const float* b1    = (const float*)d_in[5];
  const float* W2    = (const float*)d_in[6];
  const float* b2    = (const float*)d_in[7];
  const float* lns   = (const float*)d_in[8];
  const float* lnb   = (const float*)d_in[9];
  float* out = (float*)d_out;

  char* ws = (char*)d_ws;
  unsigned short* wall = (unsigned short*)ws;              // 131,072 B (8 swizzled windows)
  unsigned short* nfb  = (unsigned short*)(ws + 131072);   // 25,600,000 B

  prep_weights<<<(384 * 128 + 128 * 128) / 256, 256, 0, stream>>>(W1, W2, wall);
  prep_nfeat<<<2048, 256, 0, stream>>>(nfeat, (unsigned*)nfb, out + (size_t)E_N * 128);

  int blocks = (E_N + 127) / 128;   // 4688
  fused_edge<<<blocks, 256, 0, stream>>>(efeat, srci, dsti, nfb, wall,
                                         b1, b2, lns, lnb, out);
}